// Round 10
// baseline (194.963 us; speedup 1.0000x reference)
//
#include <hip/hip_runtime.h>
#include <math.h>

// Problem constants (match reference setup_inputs)
#define SB 196   // spatial s = h*w = 14*14
#define SP 224   // s padded to 7*32 for MFMA K-steps
#define NB 8     // batch
#define NC 2048  // channels
#define ND 1024  // INTER_DIM
#define NN 80    // NUM_CLASSES
#define NW 300   // WORD_DIM
#define CH 16    // part chunks = d-tiles of k12

typedef __bf16 v8bf __attribute__((ext_vector_type(8)));
typedef __bf16 v4bf __attribute__((ext_vector_type(4)));
typedef float  f32x4 __attribute__((ext_vector_type(4)));

// ---------------------------------------------------------------------------
// K0a: v[d] = sum_e Wa[e] * W3[e][d]   (Wa @ W3), accumulated via atomics.
// ---------------------------------------------------------------------------
__global__ __launch_bounds__(256) void k0_v(const float* __restrict__ W3,
                                            const float* __restrict__ Wa,
                                            float* __restrict__ v) {
    int d  = blockIdx.x * 256 + threadIdx.x;
    int e0 = blockIdx.y * 64;
    float p = 0.f;
    #pragma unroll 8
    for (int e = e0; e < e0 + 64; ++e) {
        p += Wa[e] * W3[(size_t)e * ND + d];   // coalesced over d
    }
    atomicAdd(&v[d], p);
}

// ---------------------------------------------------------------------------
// K0b: fwd[n][d] = sum_w word[n][w] * W2[d][w]; emits
//   wpack[n][d] = { 2*log2(e)*fwd, -2*v[d] }
// k12 computes logit' = sum_d wy / (1 + 2^(F*wx)) = ref logit - sum(v)
// (s-uniform constant, cancels in softmax over s). Runs after k0_v.
// ---------------------------------------------------------------------------
__global__ __launch_bounds__(256) void k0_fwd(const float* __restrict__ word,
                                              const float* __restrict__ W2,
                                              const float* __restrict__ v,
                                              float2* __restrict__ wpack) {
    __shared__ __align__(16) float lword[NW];
    int n = blockIdx.x;
    int d = blockIdx.y * 256 + threadIdx.x;
    for (int i = threadIdx.x; i < NW; i += 256) lword[i] = word[(size_t)n * NW + i];
    __syncthreads();
    const float4* wr = (const float4*)(W2 + (size_t)d * NW);
    const float4* l4 = (const float4*)lword;
    float acc = 0.f;
    #pragma unroll 5
    for (int i = 0; i < NW / 4; ++i) {
        float4 a = wr[i], b = l4[i];
        acc += a.x * b.x + a.y * b.y + a.z * b.z + a.w * b.w;
    }
    float2 o;
    o.x = 2.8853900817779268f * acc;   // 2*log2(e) * fwd[n][d]
    o.y = -2.f * v[d];
    wpack[(size_t)n * ND + d] = o;
}

// ---------------------------------------------------------------------------
// kcast_x: ONE pass over X [b][c][s] fp32 producing
//   Xt  [b][s][c]  bf16 (transposed, for k12 staging)
//   Xhi/Xlo [b][c][224] bf16 split (for k3), zero s-pad
// grid (32 c-tiles, 4 s-tiles, 9): z<8 = batch slice; z==8 = W1 fp32->bf16.
// ---------------------------------------------------------------------------
__global__ __launch_bounds__(256) void kcast_x(const float* __restrict__ X,
                                               const float* __restrict__ W1,
                                               __bf16* __restrict__ Xt,
                                               __bf16* __restrict__ Xhi,
                                               __bf16* __restrict__ Xlo,
                                               __bf16* __restrict__ W1b) {
    const int t = threadIdx.x;
    if (blockIdx.z == 8) {
        unsigned int slice_tid = (blockIdx.x * 4 + blockIdx.y) * 256 + t;
        #pragma unroll 4
        for (int r = 0; r < 16; ++r) {
            size_t i = ((size_t)slice_tid + (size_t)r * 32768) * 4;
            float4 f = *(const float4*)(W1 + i);
            v4bf o;
            o[0] = (__bf16)f.x; o[1] = (__bf16)f.y;
            o[2] = (__bf16)f.z; o[3] = (__bf16)f.w;
            *(v4bf*)(W1b + i) = o;
        }
        return;
    }
    __shared__ float tile[64][65];   // [c][s], +1 pad
    const int b  = blockIdx.z;
    const int c0 = blockIdx.x * 64;
    const int s0 = blockIdx.y * 64;
    const float* Xb = X + (size_t)b * NC * SB;
    {   // read: coalesced over s
        int ss = t & 63, cbase = t >> 6;
        #pragma unroll
        for (int r = 0; r < 16; ++r) {
            int cc = cbase + 4 * r;
            float val = (s0 + ss < SB) ? Xb[(size_t)(c0 + cc) * SB + s0 + ss] : 0.f;
            tile[cc][ss] = val;
        }
    }
    __syncthreads();
    {   // write 1: Xt transposed, coalesced over c
        int cc = t & 63, sbase = t >> 6;
        #pragma unroll
        for (int r = 0; r < 16; ++r) {
            int ss = sbase + 4 * r;
            if (s0 + ss < SB)
                Xt[((size_t)b * SB + s0 + ss) * NC + c0 + cc] = (__bf16)tile[cc][ss];
        }
    }
    {   // write 2: Xhi/Xlo direct orientation; zero the pad
        int ss = t & 63, cbase = t >> 6;
        int sg = s0 + ss;
        #pragma unroll
        for (int r = 0; r < 16; ++r) {
            int cc = cbase + 4 * r;
            if (sg < SP) {
                float val = (sg < SB) ? tile[cc][ss] : 0.f;
                __bf16 h = (__bf16)val;
                __bf16 l = (__bf16)(val - (float)h);
                size_t base = ((size_t)b * NC + c0 + cc) * SP + sg;
                Xhi[base] = h;
                Xlo[base] = l;
            }
        }
    }
}

// ---------------------------------------------------------------------------
// K12 (fused k1+k2a): MFMA computes the 64d x 64s F-tile (EXACT R3-proven
// K-loop/staging), acc -> LDS tile, then per-wave logit partials:
//   part[dtile][b][n][s] = sum_{d in tile} wy[n,d] / (1 + 2^(F[d,s]*wx[n,d]))
// F is never materialized in global memory. grid (16 d-tiles, 4 s-tiles, 8 b),
// block 256 (4 waves; MFMA: 32x32 quadrants; compute: wave w owns n in
// [20w, 20w+20), lane = s_local).
// ---------------------------------------------------------------------------
#define PITCH 40   // lA/lB row pitch in shorts
#define FP 66      // ldsF row pitch in floats: 2-way bank alias only
__global__ __launch_bounds__(256) void k12(const __bf16* __restrict__ Xt,
                                           const __bf16* __restrict__ W1b,
                                           const float2* __restrict__ wpack,
                                           float* __restrict__ part) {
    __shared__ __align__(16) __bf16 lA[64 * PITCH];
    __shared__ __align__(16) __bf16 lB[64 * PITCH];
    __shared__ __align__(16) float ldsF[64 * FP];
    const int t    = threadIdx.x;
    const int d0   = blockIdx.x * 64;
    const int s0   = blockIdx.y * 64;
    const int b    = blockIdx.z;
    const int lane = t & 63;
    const int wave = t >> 6;
    const int doff = (wave & 1) * 32;
    const int soff = (wave >> 1) * 32;
    const int quad = lane >> 4;
    const int l16  = lane & 15;

    f32x4 acc[2][2] = {};

    const int rr = t >> 2;
    const int cc = (t & 3) * 8;
    const bool sv = (s0 + rr) < SB;
    const __bf16* Ag = W1b + (size_t)(d0 + rr) * NC + cc;
    const __bf16* Bg = Xt + ((size_t)b * SB + (sv ? (s0 + rr) : 0)) * NC + cc;
    __bf16* lAw = lA + rr * PITCH + cc;
    __bf16* lBw = lB + rr * PITCH + cc;

    const __bf16* rA0 = lA + (doff + l16) * PITCH + quad * 8;
    const __bf16* rA1 = rA0 + 16 * PITCH;
    const __bf16* rB0 = lB + (soff + l16) * PITCH + quad * 8;
    const __bf16* rB1 = rB0 + 16 * PITCH;

    for (int k0 = 0; k0 < NC; k0 += 32) {
        uint4 a = *(const uint4*)(Ag + k0);
        uint4 bv = sv ? *(const uint4*)(Bg + k0) : make_uint4(0u, 0u, 0u, 0u);
        __syncthreads();
        *(uint4*)lAw = a;
        *(uint4*)lBw = bv;
        __syncthreads();
        v8bf a0 = *(const v8bf*)rA0;
        v8bf a1 = *(const v8bf*)rA1;
        v8bf b0 = *(const v8bf*)rB0;
        v8bf b1 = *(const v8bf*)rB1;
        acc[0][0] = __builtin_amdgcn_mfma_f32_16x16x32_bf16(a0, b0, acc[0][0], 0, 0, 0);
        acc[0][1] = __builtin_amdgcn_mfma_f32_16x16x32_bf16(a0, b1, acc[0][1], 0, 0, 0);
        acc[1][0] = __builtin_amdgcn_mfma_f32_16x16x32_bf16(a1, b0, acc[1][0], 0, 0, 0);
        acc[1][1] = __builtin_amdgcn_mfma_f32_16x16x32_bf16(a1, b1, acc[1][1], 0, 0, 0);
    }
    // epilogue 1: acc -> LDS F-tile (ldsF is a separate region: no hazard
    // with the K-loop's lA/lB, so a single barrier after the writes suffices)
    #pragma unroll
    for (int i = 0; i < 2; ++i) {
        #pragma unroll
        for (int j = 0; j < 2; ++j) {
            int sl = soff + j * 16 + l16;
            #pragma unroll
            for (int r = 0; r < 4; ++r) {
                int dl = doff + i * 16 + quad * 4 + r;
                ldsF[dl * FP + sl] = acc[i][j][r];
            }
        }
    }
    __syncthreads();
    // epilogue 2: logit partials. lane = s_local; hoist this lane's 64 F
    // values into registers (one-time ds_reads), then 20 n per wave.
    float fv[64];
    #pragma unroll
    for (int d = 0; d < 64; ++d) fv[d] = ldsF[d * FP + lane];
    const int sg = s0 + lane;
    const bool svalid = sg < SB;
    const int nbase = wave * 20;
    float* pbase = part + (((size_t)blockIdx.x * NB + b) * NN) * 256;
    for (int nn = 0; nn < 20; ++nn) {
        int n = nbase + nn;
        const float4* wp4 = (const float4*)(wpack + (size_t)n * ND + d0);
        float a2 = 0.f;
        #pragma unroll
        for (int d2 = 0; d2 < 32; ++d2) {
            float4 w = wp4[d2];   // {wx0,wy0,wx1,wy1} wave-uniform s_load
            float e0 = __builtin_amdgcn_exp2f(fv[2 * d2]     * w.x);
            float e1 = __builtin_amdgcn_exp2f(fv[2 * d2 + 1] * w.z);
            a2 = fmaf(w.y, __builtin_amdgcn_rcpf(1.f + e0), a2);
            a2 = fmaf(w.w, __builtin_amdgcn_rcpf(1.f + e1), a2);
        }
        if (svalid) pbase[(size_t)n * 256 + sg] = a2;
    }
}

// ---------------------------------------------------------------------------
// K2b: sum 16 d-tile chunks, softmax over s, write split bf16 coef.
// grid (80 n, 8 b), block 256. part slots s in [196,256) are never written
// (finite poison); they only reach acc for t>=SB, which is masked below.
// ---------------------------------------------------------------------------
__global__ __launch_bounds__(256) void k2b(const float* __restrict__ part,
                                           __bf16* __restrict__ coefh,
                                           __bf16* __restrict__ coefl) {
    __shared__ float red[256];
    const int n = blockIdx.x;
    const int b = blockIdx.y;
    const int t = threadIdx.x;
    float acc = 0.f;
    #pragma unroll
    for (int ch = 0; ch < CH; ++ch)
        acc += part[(((size_t)ch * NB + b) * NN + n) * 256 + t];

    red[t] = (t < SB) ? acc : -1e30f;
    __syncthreads();
    #pragma unroll
    for (int off = 128; off > 0; off >>= 1) {
        if (t < off) red[t] = fmaxf(red[t], red[t + off]);
        __syncthreads();
    }
    float m = red[0];
    __syncthreads();
    float p = (t < SB) ? __expf(acc - m) : 0.f;
    red[t] = p;
    __syncthreads();
    #pragma unroll
    for (int off = 128; off > 0; off >>= 1) {
        if (t < off) red[t] += red[t + off];
        __syncthreads();
    }
    float inv = 1.f / red[0];
    if (t < SP) {
        float val = (t < SB) ? p * inv : 0.f;
        __bf16 h = (__bf16)val;
        __bf16 l = (__bf16)(val - (float)h);
        size_t base = ((size_t)b * NN + n) * SP + t;
        coefh[base] = h;
        coefl[base] = l;
    }
}

// ---------------------------------------------------------------------------
// K3 (MFMA, split precision): out[b][n][c] = sum_s coef[b][n][s] * X[b][c][s]
// out ~= Ah*Bh + Al*Bh + Ah*Bl. grid (32 c-tiles, 8 b), block 256.
// ---------------------------------------------------------------------------
__global__ __launch_bounds__(256) void k3_mfma(const __bf16* __restrict__ Xhi,
                                               const __bf16* __restrict__ Xlo,
                                               const __bf16* __restrict__ coefh,
                                               const __bf16* __restrict__ coefl,
                                               float* __restrict__ out) {
    const int t     = threadIdx.x;
    const int wave  = t >> 6;
    const int lane  = t & 63;
    const int quad  = lane >> 4;
    const int l16   = lane & 15;
    const int b     = blockIdx.y;
    const int cbase = blockIdx.x * 64 + wave * 16;

    const __bf16* Bh = Xhi + ((size_t)b * NC + cbase + l16) * SP + quad * 8;
    const __bf16* Bl = Xlo + ((size_t)b * NC + cbase + l16) * SP + quad * 8;
    const __bf16* Ah = coefh + ((size_t)b * NN + l16) * SP + quad * 8;
    const __bf16* Al = coefl + ((size_t)b * NN + l16) * SP + quad * 8;

    f32x4 acc[5] = {};

    #pragma unroll
    for (int k0 = 0; k0 < SP; k0 += 32) {
        v8bf bh = *(const v8bf*)(Bh + k0);
        v8bf bl = *(const v8bf*)(Bl + k0);
        #pragma unroll
        for (int mt = 0; mt < 5; ++mt) {
            v8bf ah = *(const v8bf*)(Ah + (size_t)mt * 16 * SP + k0);
            v8bf al = *(const v8bf*)(Al + (size_t)mt * 16 * SP + k0);
            acc[mt] = __builtin_amdgcn_mfma_f32_16x16x32_bf16(ah, bh, acc[mt], 0, 0, 0);
            acc[mt] = __builtin_amdgcn_mfma_f32_16x16x32_bf16(al, bh, acc[mt], 0, 0, 0);
            acc[mt] = __builtin_amdgcn_mfma_f32_16x16x32_bf16(ah, bl, acc[mt], 0, 0, 0);
        }
    }
    #pragma unroll
    for (int mt = 0; mt < 5; ++mt) {
        #pragma unroll
        for (int r = 0; r < 4; ++r) {
            int n = mt * 16 + quad * 4 + r;
            out[((size_t)b * NN + n) * NC + cbase + l16] = acc[mt][r];
        }
    }
}

// ---------------------------------------------------------------------------
// Workspace layout — NO aliasing (ws ~256 MB; peak use ~43 MB):
//   v(4K) | wpack(640K) | part(10.5M) | coefh(280K) | coefl(280K) |
//   W1b(4M) | Xt(6.42M) | Xhi(7.34M) | Xlo(7.34M)     (F is gone)
// ---------------------------------------------------------------------------
extern "C" void kernel_launch(void* const* d_in, const int* in_sizes, int n_in,
                              void* d_out, int out_size, void* d_ws, size_t ws_size,
                              hipStream_t stream) {
    const float* X    = (const float*)d_in[0];  // [8][2048][196]
    const float* word = (const float*)d_in[1];  // [80][300]
    const float* W1   = (const float*)d_in[2];  // [1024][2048]
    const float* W2   = (const float*)d_in[3];  // [1024][300]
    const float* W3   = (const float*)d_in[4];  // [1024][1024]
    // d_in[5] = b3, d_in[7] = ba: cancel in softmax (uniform over s) -> unused
    const float* Wa   = (const float*)d_in[6];  // [1][1024]
    float* out = (float*)d_out;

    char* ws = (char*)d_ws;
    float*  v     = (float*)ws;                             // 1024 f
    float2* wpack = (float2*)(v + ND);                      // 80*1024 float2
    float*  part  = (float*)(wpack + (size_t)NN * ND);      // 16*8*80*256 f
    __bf16* coefh = (__bf16*)(part + (size_t)CH * NB * NN * 256);
    __bf16* coefl = coefh + (size_t)NB * NN * SP;
    __bf16* W1b   = coefl + (size_t)NB * NN * SP;           // 4.00 MB
    __bf16* Xt    = W1b + (size_t)ND * NC;                  // 6.42 MB
    __bf16* Xhi   = Xt + (size_t)NB * SB * NC;              // 7.34 MB
    __bf16* Xlo   = Xhi + (size_t)NB * NC * SP;             // 7.34 MB

    hipMemsetAsync(v, 0, ND * sizeof(float), stream);
    k0_v   <<<dim3(4, 16),       256, 0, stream>>>(W3, Wa, v);
    k0_fwd <<<dim3(NN, 4),       256, 0, stream>>>(word, W2, v, wpack);
    kcast_x<<<dim3(32, 4, 9),    256, 0, stream>>>(X, W1, Xt, Xhi, Xlo, W1b);
    k12    <<<dim3(16, 4, NB),   256, 0, stream>>>(Xt, W1b, wpack, part);
    k2b    <<<dim3(NN, NB),      256, 0, stream>>>(part, coefh, coefl);
    k3_mfma<<<dim3(NC / 64, NB), 256, 0, stream>>>(Xhi, Xlo, coefh, coefl, out);
}

// Round 11
// 190.965 us; speedup vs baseline: 1.0209x; 1.0209x over previous
//
#include <hip/hip_runtime.h>
#include <math.h>

// Problem constants (match reference setup_inputs)
#define SB 196   // spatial s = h*w = 14*14
#define SP 224   // s padded to 7*32 for MFMA K-steps
#define NB 8     // batch
#define NC 2048  // channels
#define ND 1024  // INTER_DIM
#define NN 80    // NUM_CLASSES
#define NW 300   // WORD_DIM
#define CH 16    // d-chunks in k2a
#define DCH (ND / CH)   // 64

typedef __bf16 v8bf __attribute__((ext_vector_type(8)));
typedef __bf16 v4bf __attribute__((ext_vector_type(4)));
typedef float  f32x4 __attribute__((ext_vector_type(4)));

// ---------------------------------------------------------------------------
// K0a: v[d] = sum_e Wa[e] * W3[e][d]   (Wa @ W3), accumulated via atomics.
// ---------------------------------------------------------------------------
__global__ __launch_bounds__(256) void k0_v(const float* __restrict__ W3,
                                            const float* __restrict__ Wa,
                                            float* __restrict__ v) {
    int d  = blockIdx.x * 256 + threadIdx.x;
    int e0 = blockIdx.y * 64;
    float p = 0.f;
    #pragma unroll 8
    for (int e = e0; e < e0 + 64; ++e) {
        p += Wa[e] * W3[(size_t)e * ND + d];   // coalesced over d
    }
    atomicAdd(&v[d], p);
}

// ---------------------------------------------------------------------------
// K0b: fwd[n][d] = sum_w word[n][w] * W2[d][w]; emits
//   wpack[n][d] = { 2*log2(e)*fwd, -2*v[d] }
// k2a computes logit' = sum_d wy / (1 + 2^(F*wx)) = ref logit - sum(v)
// (s-uniform constant, cancels in softmax over s). Runs after k0_v.
// ---------------------------------------------------------------------------
__global__ __launch_bounds__(256) void k0_fwd(const float* __restrict__ word,
                                              const float* __restrict__ W2,
                                              const float* __restrict__ v,
                                              float2* __restrict__ wpack) {
    __shared__ __align__(16) float lword[NW];
    int n = blockIdx.x;
    int d = blockIdx.y * 256 + threadIdx.x;
    for (int i = threadIdx.x; i < NW; i += 256) lword[i] = word[(size_t)n * NW + i];
    __syncthreads();
    const float4* wr = (const float4*)(W2 + (size_t)d * NW);
    const float4* l4 = (const float4*)lword;
    float acc = 0.f;
    #pragma unroll 5
    for (int i = 0; i < NW / 4; ++i) {
        float4 a = wr[i], b = l4[i];
        acc += a.x * b.x + a.y * b.y + a.z * b.z + a.w * b.w;
    }
    float2 o;
    o.x = 2.8853900817779268f * acc;   // 2*log2(e) * fwd[n][d]
    o.y = -2.f * v[d];
    wpack[(size_t)n * ND + d] = o;
}

// ---------------------------------------------------------------------------
// kcast_x: ONE pass over X [b][c][s] fp32 producing
//   Xt  [b][s][c]  bf16 (transposed, for k1 staging)
//   Xhi/Xlo [b][c][224] bf16 split (for k3), zero s-pad
// grid (32 c-tiles, 4 s-tiles, 9): z<8 = batch slice; z==8 = W1 fp32->bf16.
// ---------------------------------------------------------------------------
__global__ __launch_bounds__(256) void kcast_x(const float* __restrict__ X,
                                               const float* __restrict__ W1,
                                               __bf16* __restrict__ Xt,
                                               __bf16* __restrict__ Xhi,
                                               __bf16* __restrict__ Xlo,
                                               __bf16* __restrict__ W1b) {
    const int t = threadIdx.x;
    if (blockIdx.z == 8) {
        unsigned int slice_tid = (blockIdx.x * 4 + blockIdx.y) * 256 + t;
        #pragma unroll 4
        for (int r = 0; r < 16; ++r) {
            size_t i = ((size_t)slice_tid + (size_t)r * 32768) * 4;
            float4 f = *(const float4*)(W1 + i);
            v4bf o;
            o[0] = (__bf16)f.x; o[1] = (__bf16)f.y;
            o[2] = (__bf16)f.z; o[3] = (__bf16)f.w;
            *(v4bf*)(W1b + i) = o;
        }
        return;
    }
    __shared__ float tile[64][65];   // [c][s], +1 pad
    const int b  = blockIdx.z;
    const int c0 = blockIdx.x * 64;
    const int s0 = blockIdx.y * 64;
    const float* Xb = X + (size_t)b * NC * SB;
    {   // read: coalesced over s
        int ss = t & 63, cbase = t >> 6;
        #pragma unroll
        for (int r = 0; r < 16; ++r) {
            int cc = cbase + 4 * r;
            float val = (s0 + ss < SB) ? Xb[(size_t)(c0 + cc) * SB + s0 + ss] : 0.f;
            tile[cc][ss] = val;
        }
    }
    __syncthreads();
    {   // write 1: Xt transposed, coalesced over c
        int cc = t & 63, sbase = t >> 6;
        #pragma unroll
        for (int r = 0; r < 16; ++r) {
            int ss = sbase + 4 * r;
            if (s0 + ss < SB)
                Xt[((size_t)b * SB + s0 + ss) * NC + c0 + cc] = (__bf16)tile[cc][ss];
        }
    }
    {   // write 2: Xhi/Xlo direct orientation; zero the pad
        int ss = t & 63, cbase = t >> 6;
        int sg = s0 + ss;
        #pragma unroll
        for (int r = 0; r < 16; ++r) {
            int cc = cbase + 4 * r;
            if (sg < SP) {
                float val = (sg < SB) ? tile[cc][ss] : 0.f;
                __bf16 h = (__bf16)val;
                __bf16 l = (__bf16)(val - (float)h);
                size_t base = ((size_t)b * NC + c0 + cc) * SP + sg;
                Xhi[base] = h;
                Xlo[base] = l;
            }
        }
    }
}

// ---------------------------------------------------------------------------
// K1 (MFMA): F[b][d][s] = sum_c W1[d][c] * X[b][c][s], bf16 inputs, fp32 out.
// Block tile 64d x 64s, 4 waves each own a 32x32 quadrant (2x2 16x16 frags).
// K-step 32. grid (16 d-tiles, 4 s-tiles, 8 b), block 256.
// EXACT R3/R6-R9-proven version (BK=64+prefetch banned; R10 fusion banned).
// ---------------------------------------------------------------------------
#define PITCH 40
__global__ __launch_bounds__(256) void k1_mfma(const __bf16* __restrict__ Xt,
                                               const __bf16* __restrict__ W1b,
                                               float* __restrict__ F) {
    __shared__ __align__(16) __bf16 lA[64 * PITCH];
    __shared__ __align__(16) __bf16 lB[64 * PITCH];
    const int t    = threadIdx.x;
    const int d0   = blockIdx.x * 64;
    const int s0   = blockIdx.y * 64;
    const int b    = blockIdx.z;
    const int lane = t & 63;
    const int wave = t >> 6;
    const int doff = (wave & 1) * 32;
    const int soff = (wave >> 1) * 32;
    const int quad = lane >> 4;
    const int l16  = lane & 15;

    f32x4 acc[2][2] = {};

    const int rr = t >> 2;
    const int cc = (t & 3) * 8;
    const bool sv = (s0 + rr) < SB;
    const __bf16* Ag = W1b + (size_t)(d0 + rr) * NC + cc;
    const __bf16* Bg = Xt + ((size_t)b * SB + (sv ? (s0 + rr) : 0)) * NC + cc;
    __bf16* lAw = lA + rr * PITCH + cc;
    __bf16* lBw = lB + rr * PITCH + cc;

    const __bf16* rA0 = lA + (doff + l16) * PITCH + quad * 8;
    const __bf16* rA1 = rA0 + 16 * PITCH;
    const __bf16* rB0 = lB + (soff + l16) * PITCH + quad * 8;
    const __bf16* rB1 = rB0 + 16 * PITCH;

    for (int k0 = 0; k0 < NC; k0 += 32) {
        uint4 a = *(const uint4*)(Ag + k0);
        uint4 bv = sv ? *(const uint4*)(Bg + k0) : make_uint4(0u, 0u, 0u, 0u);
        __syncthreads();
        *(uint4*)lAw = a;
        *(uint4*)lBw = bv;
        __syncthreads();
        v8bf a0 = *(const v8bf*)rA0;
        v8bf a1 = *(const v8bf*)rA1;
        v8bf b0 = *(const v8bf*)rB0;
        v8bf b1 = *(const v8bf*)rB1;
        acc[0][0] = __builtin_amdgcn_mfma_f32_16x16x32_bf16(a0, b0, acc[0][0], 0, 0, 0);
        acc[0][1] = __builtin_amdgcn_mfma_f32_16x16x32_bf16(a0, b1, acc[0][1], 0, 0, 0);
        acc[1][0] = __builtin_amdgcn_mfma_f32_16x16x32_bf16(a1, b0, acc[1][0], 0, 0, 0);
        acc[1][1] = __builtin_amdgcn_mfma_f32_16x16x32_bf16(a1, b1, acc[1][1], 0, 0, 0);
    }
    float* Fb = F + (size_t)b * ND * SB;
    #pragma unroll
    for (int i = 0; i < 2; ++i) {
        #pragma unroll
        for (int j = 0; j < 2; ++j) {
            int s = s0 + soff + j * 16 + l16;
            if (s < SB) {
                #pragma unroll
                for (int r = 0; r < 4; ++r) {
                    int d = d0 + doff + i * 16 + quad * 4 + r;
                    Fb[(size_t)d * SB + s] = acc[i][j][r];
                }
            }
        }
    }
}

// ---------------------------------------------------------------------------
// K2a v4: partial logits, 8-way n-tiling x 16 d-chunks.
// part[ch][b][n][s] = sum_{d in chunk} wy/(1 + 2^(F*wx))
// grid (10 n-groups, 7 bs-tiles, 16 ch) = 1120 blocks, block 256.
// Per d-pair iter: 2 coalesced F loads feed 32 trans ops (16 independent
// chains) -> load latency fully covered by trans issue (~256 cyc/pair).
// wpack addresses are block-uniform -> s_load_dwordx4.
// ---------------------------------------------------------------------------
__global__ __launch_bounds__(256) void k2a(const float* __restrict__ F,
                                           const float2* __restrict__ wpack,
                                           float* __restrict__ part) {
    const int n0  = blockIdx.x * 8;
    const int ch  = blockIdx.z;
    const int idx = blockIdx.y * 256 + threadIdx.x;   // (b,s) flat, valid <1568
    const bool valid = idx < (NB * SB);
    const int iv = valid ? idx : 0;
    const int b  = iv / SB;          // magic-mul div by 196
    const int s  = iv - b * SB;
    const float*  Fp    = F + ((size_t)b * ND + ch * DCH) * SB + s;
    const float2* wbase = wpack + ch * DCH;
    float a[8] = {};
    #pragma unroll 2
    for (int d2 = 0; d2 < DCH / 2; ++d2) {
        float f0 = Fp[(size_t)(2 * d2)     * SB];
        float f1 = Fp[(size_t)(2 * d2 + 1) * SB];
        #pragma unroll
        for (int j = 0; j < 8; ++j) {
            // block-uniform address -> scalar s_load_dwordx4
            float4 w = *(const float4*)(wbase + (size_t)(n0 + j) * ND + 2 * d2);
            float e0 = __builtin_amdgcn_exp2f(f0 * w.x);
            float e1 = __builtin_amdgcn_exp2f(f1 * w.z);
            a[j] = fmaf(w.y, __builtin_amdgcn_rcpf(1.f + e0), a[j]);
            a[j] = fmaf(w.w, __builtin_amdgcn_rcpf(1.f + e1), a[j]);
        }
    }
    if (valid) {
        size_t base = ((size_t)ch * NB + b) * NN;
        #pragma unroll
        for (int j = 0; j < 8; ++j)
            part[(base + n0 + j) * 256 + s] = a[j];
    }
}

// ---------------------------------------------------------------------------
// K2b: sum 16 chunks, softmax over s, write split bf16 coef (SP-padded).
// grid (80 n, 8 b), block 256. part slots s in [196,256) are never written
// (finite poison); they only reach acc for t>=SB, which is masked below.
// ---------------------------------------------------------------------------
__global__ __launch_bounds__(256) void k2b(const float* __restrict__ part,
                                           __bf16* __restrict__ coefh,
                                           __bf16* __restrict__ coefl) {
    __shared__ float red[256];
    const int n = blockIdx.x;
    const int b = blockIdx.y;
    const int t = threadIdx.x;
    float acc = 0.f;
    #pragma unroll
    for (int ch = 0; ch < CH; ++ch)
        acc += part[(((size_t)ch * NB + b) * NN + n) * 256 + t];

    red[t] = (t < SB) ? acc : -1e30f;
    __syncthreads();
    #pragma unroll
    for (int off = 128; off > 0; off >>= 1) {
        if (t < off) red[t] = fmaxf(red[t], red[t + off]);
        __syncthreads();
    }
    float m = red[0];
    __syncthreads();
    float p = (t < SB) ? __expf(acc - m) : 0.f;
    red[t] = p;
    __syncthreads();
    #pragma unroll
    for (int off = 128; off > 0; off >>= 1) {
        if (t < off) red[t] += red[t + off];
        __syncthreads();
    }
    float inv = 1.f / red[0];
    if (t < SP) {
        float val = (t < SB) ? p * inv : 0.f;
        __bf16 h = (__bf16)val;
        __bf16 l = (__bf16)(val - (float)h);
        size_t base = ((size_t)b * NN + n) * SP + t;
        coefh[base] = h;
        coefl[base] = l;
    }
}

// ---------------------------------------------------------------------------
// K3 (MFMA, split precision): out[b][n][c] = sum_s coef[b][n][s] * X[b][c][s]
// out ~= Ah*Bh + Al*Bh + Ah*Bl. grid (32 c-tiles, 8 b), block 256.
// ---------------------------------------------------------------------------
__global__ __launch_bounds__(256) void k3_mfma(const __bf16* __restrict__ Xhi,
                                               const __bf16* __restrict__ Xlo,
                                               const __bf16* __restrict__ coefh,
                                               const __bf16* __restrict__ coefl,
                                               float* __restrict__ out) {
    const int t     = threadIdx.x;
    const int wave  = t >> 6;
    const int lane  = t & 63;
    const int quad  = lane >> 4;
    const int l16   = lane & 15;
    const int b     = blockIdx.y;
    const int cbase = blockIdx.x * 64 + wave * 16;

    const __bf16* Bh = Xhi + ((size_t)b * NC + cbase + l16) * SP + quad * 8;
    const __bf16* Bl = Xlo + ((size_t)b * NC + cbase + l16) * SP + quad * 8;
    const __bf16* Ah = coefh + ((size_t)b * NN + l16) * SP + quad * 8;
    const __bf16* Al = coefl + ((size_t)b * NN + l16) * SP + quad * 8;

    f32x4 acc[5] = {};

    #pragma unroll
    for (int k0 = 0; k0 < SP; k0 += 32) {
        v8bf bh = *(const v8bf*)(Bh + k0);
        v8bf bl = *(const v8bf*)(Bl + k0);
        #pragma unroll
        for (int mt = 0; mt < 5; ++mt) {
            v8bf ah = *(const v8bf*)(Ah + (size_t)mt * 16 * SP + k0);
            v8bf al = *(const v8bf*)(Al + (size_t)mt * 16 * SP + k0);
            acc[mt] = __builtin_amdgcn_mfma_f32_16x16x32_bf16(ah, bh, acc[mt], 0, 0, 0);
            acc[mt] = __builtin_amdgcn_mfma_f32_16x16x32_bf16(al, bh, acc[mt], 0, 0, 0);
            acc[mt] = __builtin_amdgcn_mfma_f32_16x16x32_bf16(ah, bl, acc[mt], 0, 0, 0);
        }
    }
    #pragma unroll
    for (int mt = 0; mt < 5; ++mt) {
        #pragma unroll
        for (int r = 0; r < 4; ++r) {
            int n = mt * 16 + quad * 4 + r;
            out[((size_t)b * NN + n) * NC + cbase + l16] = acc[mt][r];
        }
    }
}

// ---------------------------------------------------------------------------
// Workspace layout — NO aliasing (ws ~256 MB; peak use ~43 MB):
//   v(4K) | wpack(640K) | part(10.5M) | coefh(280K) | coefl(280K) |
//   W1b(4M) | Xt(6.42M) | F(6.42M) | Xhi(7.34M) | Xlo(7.34M)
// ---------------------------------------------------------------------------
extern "C" void kernel_launch(void* const* d_in, const int* in_sizes, int n_in,
                              void* d_out, int out_size, void* d_ws, size_t ws_size,
                              hipStream_t stream) {
    const float* X    = (const float*)d_in[0];  // [8][2048][196]
    const float* word = (const float*)d_in[1];  // [80][300]
    const float* W1   = (const float*)d_in[2];  // [1024][2048]
    const float* W2   = (const float*)d_in[3];  // [1024][300]
    const float* W3   = (const float*)d_in[4];  // [1024][1024]
    // d_in[5] = b3, d_in[7] = ba: cancel in softmax (uniform over s) -> unused
    const float* Wa   = (const float*)d_in[6];  // [1][1024]
    float* out = (float*)d_out;

    char* ws = (char*)d_ws;
    float*  v     = (float*)ws;                             // 1024 f
    float2* wpack = (float2*)(v + ND);                      // 80*1024 float2
    float*  part  = (float*)(wpack + (size_t)NN * ND);      // 16*8*80*256 f
    __bf16* coefh = (__bf16*)(part + (size_t)CH * NB * NN * 256);
    __bf16* coefl = coefh + (size_t)NB * NN * SP;
    __bf16* W1b   = coefl + (size_t)NB * NN * SP;           // 4.00 MB
    __bf16* Xt    = W1b + (size_t)ND * NC;                  // 6.42 MB
    float*  F     = (float*)(Xt + (size_t)NB * SB * NC);    // 6.42 MB
    __bf16* Xhi   = (__bf16*)(F + (size_t)NB * ND * SB);    // 7.34 MB
    __bf16* Xlo   = Xhi + (size_t)NB * NC * SP;             // 7.34 MB

    hipMemsetAsync(v, 0, ND * sizeof(float), stream);
    k0_v   <<<dim3(4, 16),        256, 0, stream>>>(W3, Wa, v);
    k0_fwd <<<dim3(NN, 4),        256, 0, stream>>>(word, W2, v, wpack);
    kcast_x<<<dim3(32, 4, 9),     256, 0, stream>>>(X, W1, Xt, Xhi, Xlo, W1b);
    k1_mfma<<<dim3(16, 4, NB),    256, 0, stream>>>(Xt, W1b, F);
    k2a    <<<dim3(10, 7, CH),    256, 0, stream>>>(F, wpack, part);
    k2b    <<<dim3(NN, NB),       256, 0, stream>>>(part, coefh, coefl);
    k3_mfma<<<dim3(NC / 64, NB),  256, 0, stream>>>(Xhi, Xlo, coefh, coefl, out);
}